// Round 2
// baseline (717.461 us; speedup 1.0000x reference)
//
#include <hip/hip_runtime.h>
#include <hip/hip_bf16.h>

// ---- problem constants (match reference) ----
#define TS 8192     // tokens S
#define TM 4096     // model dim M
#define TE 64       // experts E
#define TCAP 128    // capacity
#define KS 8        // split-K chunks
#define KCHUNK (TM / KS)      // 512
#define BK 16
#define NTILE (KCHUNK / BK)   // 32
#define BM 128                // tokens per gemm block
#define GEMM_BLOCKS 512       // 64 token-blocks * 8 k-chunks
#define K1_GRID 2048
#define NFILL (K1_GRID - GEMM_BLOCKS)   // 1536

constexpr size_t CWsz = (size_t)TS * TE * TCAP;   // 67108864 per big output
constexpr size_t NOUT = 1 + 2 * CWsz + TE;        // 134217793 floats
constexpr size_t NF4  = (NOUT - 1) / 4;           // 33554448 float4s

// ================= K1: zero-fill d_out (1536 blocks) CONCURRENT with
// split-K fp32 GEMM partials (512 blocks). Roles interleaved via *5 swizzle
// so gemm blocks hit all XCDs (blockIdx%8 round-robin). =================
__global__ __launch_bounds__(256) void k1_fill_gemm(
    const float* __restrict__ x, const float* __restrict__ wg,
    float* __restrict__ part, float* __restrict__ me, float* __restrict__ out) {
  const int tid = threadIdx.x;
  const int v = (blockIdx.x * 5) & (K1_GRID - 1);   // bijective swizzle

  __shared__ float As[BK][132];   // stride 132: staging writes & reads <=2-way
  __shared__ float Ws[BK][68];

  if (v >= GEMM_BLOCKS) {
    // ---- fill role: stream zeros over the 537MB output ----
    const int fid = v - GEMM_BLOCKS;                // 0..NFILL-1
    const float4 z = make_float4(0.f, 0.f, 0.f, 0.f);
    float4* o4 = (float4*)out;
    for (size_t i = (size_t)fid * 256 + tid; i < NF4; i += (size_t)NFILL * 256)
      o4[i] = z;
    if (fid == 0) {
      if (tid == 0) out[NOUT - 1] = 0.0f;           // tail element
      if (tid < TE) me[tid] = 0.0f;                 // zero me for K2 atomics
    }
    return;
  }

  // ---- gemm role: C[128 tok x 64 e] partial over one 512-wide k-chunk ----
  const int gid = v;
  const int t0 = (gid & 63) * BM;
  const int k0 = (gid >> 6) * KCHUNK;
  const int tg = tid >> 3;      // token group: 4 tokens
  const int eg = tid & 7;       // expert group: 8 experts

  float acc[4][8] = {};
  float4 ra[2], rw;

  auto load = [&](int kt) {
    const int kb = k0 + kt * BK;
#pragma unroll
    for (int i = 0; i < 2; i++) {
      int idx = tid + 256 * i;
      int tok = idx >> 2, c4 = idx & 3;
      ra[i] = *(const float4*)&x[(size_t)(t0 + tok) * TM + kb + 4 * c4];
    }
    { int e = tid >> 2, c4 = tid & 3;
      rw = *(const float4*)&wg[(size_t)e * TM + kb + 4 * c4]; }
  };

  load(0);
  for (int kt = 0; kt < NTILE; kt++) {
#pragma unroll
    for (int i = 0; i < 2; i++) {
      int idx = tid + 256 * i;
      int tok = idx >> 2, c4 = idx & 3;
      As[4 * c4 + 0][tok] = ra[i].x; As[4 * c4 + 1][tok] = ra[i].y;
      As[4 * c4 + 2][tok] = ra[i].z; As[4 * c4 + 3][tok] = ra[i].w;
    }
    { int e = tid >> 2, c4 = tid & 3;
      Ws[4 * c4 + 0][e] = rw.x; Ws[4 * c4 + 1][e] = rw.y;
      Ws[4 * c4 + 2][e] = rw.z; Ws[4 * c4 + 3][e] = rw.w; }
    __syncthreads();
    if (kt + 1 < NTILE) load(kt + 1);   // reg prefetch overlaps MACs
#pragma unroll
    for (int k = 0; k < BK; k++) {
      float4 a  = *(const float4*)&As[k][tg * 4];
      float4 b0 = *(const float4*)&Ws[k][eg * 8];
      float4 b1 = *(const float4*)&Ws[k][eg * 8 + 4];
      float av[4] = {a.x, a.y, a.z, a.w};
      float bv[8] = {b0.x, b0.y, b0.z, b0.w, b1.x, b1.y, b1.z, b1.w};
#pragma unroll
      for (int i = 0; i < 4; i++)
#pragma unroll
        for (int j = 0; j < 8; j++) acc[i][j] += av[i] * bv[j];
    }
    __syncthreads();
  }
  float* dst = part + (size_t)(gid >> 6) * TS * TE;
#pragma unroll
  for (int i = 0; i < 4; i++) {
    int tok = t0 + tg * 4 + i;
    *(float4*)&dst[(size_t)tok * TE + eg * 8] =
        make_float4(acc[i][0], acc[i][1], acc[i][2], acc[i][3]);
    *(float4*)&dst[(size_t)tok * TE + eg * 8 + 4] =
        make_float4(acc[i][4], acc[i][5], acc[i][6], acc[i][7]);
  }
}

// ============ K2: K-reduce + softmax + argmax + me partial ============
// 256 blocks x 256 thr; each block: 32 tokens (4 waves x 8 iters).
__global__ __launch_bounds__(256) void k2_softmax(
    const float* __restrict__ part, float* __restrict__ gate1,
    int* __restrict__ idx1, float* __restrict__ me) {
  const int tid = threadIdx.x, w = tid >> 6, lane = tid & 63;
  const int s0 = blockIdx.x * 32;
  float mesum = 0.0f;
  for (int it = 0; it < 8; it++) {
    const int s = s0 + it * 4 + w;
    float logit = 0.0f;
#pragma unroll
    for (int p = 0; p < KS; p++)
      logit += part[((size_t)p * TS + s) * TE + lane];  // deterministic order
    // wave argmax, first-index tie-break (matches jnp.argmax)
    float mv = logit; int mi = lane;
#pragma unroll
    for (int off = 32; off; off >>= 1) {
      float ov = __shfl_xor(mv, off);
      int oi = __shfl_xor(mi, off);
      if (ov > mv || (ov == mv && oi < mi)) { mv = ov; mi = oi; }
    }
    float ex = expf(logit - mv);
    float sum = ex;
#pragma unroll
    for (int off = 32; off; off >>= 1) sum += __shfl_xor(sum, off);
    float g = ex / sum;
    mesum += g;
    if (lane == mi) { gate1[s] = g; idx1[s] = mi; }
  }
  __shared__ float red[4][64];
  red[w][lane] = mesum;
  __syncthreads();
  if (w == 0)
    atomicAdd(&me[lane], red[0][lane] + red[1][lane] + red[2][lane] + red[3][lane]);
}

// ==== K3: capacity drop — rank tokens per expert in token order ====
__global__ void k3_rank(const int* __restrict__ idx1,
                        int* __restrict__ pos, int* __restrict__ counts) {
  const int e = blockIdx.x, lane = threadIdx.x;  // 64 threads
  int base = 0;
  for (int c = 0; c < TS / 64; c++) {
    int s = c * 64 + lane;
    bool m = (idx1[s] == e);
    unsigned long long mask = __ballot(m);
    if (m) {
      int p = base + __popcll(mask & ((1ull << lane) - 1ull));
      pos[s] = (p < TCAP) ? p : -1;   // every token owned by exactly one expert
    }
    base += __popcll(mask);
  }
  if (lane == 0) counts[e] = base;    // pre-drop exp_counts
}

// ============ K4: l_aux + exp_counts + sparse scatter ============
__global__ __launch_bounds__(256) void k4_final(
    const float* __restrict__ gate1, const int* __restrict__ idx1,
    const int* __restrict__ pos, const float* __restrict__ me,
    const int* __restrict__ cnts, float* __restrict__ out) {
  if (blockIdx.x == 32) {
    if (threadIdx.x < 64) {
      const int lane = threadIdx.x;
      float vv = (me[lane] / (float)TS) * ((float)cnts[lane] / (float)TS);
      float sum = vv;
#pragma unroll
      for (int off = 32; off; off >>= 1) sum += __shfl_xor(sum, off);
      if (lane == 0) out[0] = sum * (float)TE;
      out[1 + 2 * CWsz + lane] = (float)cnts[lane];
    }
    return;
  }
  const int s = blockIdx.x * 256 + threadIdx.x;
  const int p = pos[s];
  if (p >= 0) {
    size_t off = 1 + ((size_t)s * TE + idx1[s]) * (size_t)TCAP + (size_t)p;
    out[off] = gate1[s];          // combine_weights
    out[off + CWsz] = 1.0f;       // dispatch_mask
  }
}

extern "C" void kernel_launch(void* const* d_in, const int* in_sizes, int n_in,
                              void* d_out, int out_size, void* d_ws, size_t ws_size,
                              hipStream_t stream) {
  const float* x  = (const float*)d_in[0];
  const float* wg = (const float*)d_in[1];
  float* out = (float*)d_out;

  float* part  = (float*)d_ws;                        // [KS][S][E] 16.8 MB
  float* gate1 = part + (size_t)KS * TS * TE;         // [S]
  int*   idx1  = (int*)(gate1 + TS);                  // [S]
  int*   pos   = idx1 + TS;                           // [S]
  float* me    = (float*)(pos + TS);                  // [E]
  int*   cnts  = (int*)(me + TE);                     // [E]

  k1_fill_gemm<<<K1_GRID, 256, 0, stream>>>(x, wg, part, me, out);
  k2_softmax<<<TS / 32, 256, 0, stream>>>(part, gate1, idx1, me);
  k3_rank<<<TE, 64, 0, stream>>>(idx1, pos, cnts);
  k4_final<<<33, 256, 0, stream>>>(gate1, idx1, pos, me, cnts, out);
}

// Round 3
// 698.738 us; speedup vs baseline: 1.0268x; 1.0268x over previous
//
#include <hip/hip_runtime.h>
#include <hip/hip_bf16.h>

// ---- problem constants (match reference) ----
#define TS 8192     // tokens S
#define TM 4096     // model dim M
#define TE 64       // experts E
#define TCAP 128    // capacity
#define KS 8        // split-K chunks
#define KCHUNK (TM / KS)      // 512
#define BK 16
#define NTILE (KCHUNK / BK)   // 32
#define BM 128                // tokens per gemm block
#define GEMM_BLOCKS 512       // 64 token-blocks * 8 k-chunks
#define K1_GRID 2048
#define NFILL (K1_GRID - GEMM_BLOCKS)   // 1536

constexpr size_t CWsz = (size_t)TS * TE * TCAP;   // 67108864 per big output
constexpr size_t NOUT = 1 + 2 * CWsz + TE;        // 134217793 floats
constexpr size_t NF4  = (NOUT - 1) / 4;           // 33554448 float4s

typedef float v4f __attribute__((ext_vector_type(4)));

// ================= K1: nontemporal zero-fill of d_out (1536 blocks)
// CONCURRENT with split-K fp32 GEMM partials (512 blocks). NT fill keeps
// L2/LLC clean so x half-line reuse, wg 64x reuse, and part stay cached.
__global__ __launch_bounds__(256) void k1_fill_gemm(
    const float* __restrict__ x, const float* __restrict__ wg,
    float* __restrict__ part, float* __restrict__ me, float* __restrict__ out) {
  const int tid = threadIdx.x;
  const int v = (blockIdx.x * 5) & (K1_GRID - 1);   // bijective role swizzle

  __shared__ float As[BK][132];   // all LDS reads/writes <=2-way alias (free)
  __shared__ float Ws[BK][68];

  if (v >= GEMM_BLOCKS) {
    // ---- fill role: stream zeros, bypassing caches ----
    const int fid = v - GEMM_BLOCKS;                // 0..NFILL-1
    const v4f z = {0.f, 0.f, 0.f, 0.f};
    v4f* o4 = (v4f*)out;
    for (size_t i = (size_t)fid * 256 + tid; i < NF4; i += (size_t)NFILL * 256)
      __builtin_nontemporal_store(z, &o4[i]);
    if (fid == 0) {
      if (tid == 0) out[NOUT - 1] = 0.0f;           // tail element
      if (tid < TE) me[tid] = 0.0f;                 // zero me for K2 atomics
    }
    return;
  }

  // ---- gemm role: C[128 tok x 64 e] partial over one 512-wide k-chunk ----
  const int gid = v;
  const int t0 = (gid & 63) * BM;
  const int k0 = (gid >> 6) * KCHUNK;
  const int tg = tid >> 3;      // token group: 4 tokens
  const int eg = tid & 7;       // expert group: 8 experts

  float acc[4][8] = {};
  float4 ra[2], rw;

  auto load = [&](int kt) {
    const int kb = k0 + kt * BK;
#pragma unroll
    for (int i = 0; i < 2; i++) {
      int idx = tid + 256 * i;
      int tok = idx >> 2, c4 = idx & 3;
      ra[i] = *(const float4*)&x[(size_t)(t0 + tok) * TM + kb + 4 * c4];
    }
    { int e = tid >> 2, c4 = tid & 3;
      rw = *(const float4*)&wg[(size_t)e * TM + kb + 4 * c4]; }
  };

  load(0);
  for (int kt = 0; kt < NTILE; kt++) {
#pragma unroll
    for (int i = 0; i < 2; i++) {
      int idx = tid + 256 * i;
      int tok = idx >> 2, c4 = idx & 3;
      As[4 * c4 + 0][tok] = ra[i].x; As[4 * c4 + 1][tok] = ra[i].y;
      As[4 * c4 + 2][tok] = ra[i].z; As[4 * c4 + 3][tok] = ra[i].w;
    }
    { int e = tid >> 2, c4 = tid & 3;
      Ws[4 * c4 + 0][e] = rw.x; Ws[4 * c4 + 1][e] = rw.y;
      Ws[4 * c4 + 2][e] = rw.z; Ws[4 * c4 + 3][e] = rw.w; }
    __syncthreads();
    if (kt + 1 < NTILE) load(kt + 1);   // reg prefetch overlaps MACs
#pragma unroll
    for (int k = 0; k < BK; k++) {
      float4 a  = *(const float4*)&As[k][tg * 4];
      float4 b0 = *(const float4*)&Ws[k][eg * 8];
      float4 b1 = *(const float4*)&Ws[k][eg * 8 + 4];
      float av[4] = {a.x, a.y, a.z, a.w};
      float bv[8] = {b0.x, b0.y, b0.z, b0.w, b1.x, b1.y, b1.z, b1.w};
#pragma unroll
      for (int i = 0; i < 4; i++)
#pragma unroll
        for (int j = 0; j < 8; j++) acc[i][j] += av[i] * bv[j];
    }
    __syncthreads();
  }
  float* dst = part + (size_t)(gid >> 6) * TS * TE;   // stays in LLC (fill is NT)
#pragma unroll
  for (int i = 0; i < 4; i++) {
    int tok = t0 + tg * 4 + i;
    *(float4*)&dst[(size_t)tok * TE + eg * 8] =
        make_float4(acc[i][0], acc[i][1], acc[i][2], acc[i][3]);
    *(float4*)&dst[(size_t)tok * TE + eg * 8 + 4] =
        make_float4(acc[i][4], acc[i][5], acc[i][6], acc[i][7]);
  }
}

// ============ K2: K-reduce + softmax + argmax + me partial ============
// 256 blocks x 256 thr; each block: 32 tokens (4 waves x 8 iters).
__global__ __launch_bounds__(256) void k2_softmax(
    const float* __restrict__ part, float* __restrict__ gate1,
    int* __restrict__ idx1, float* __restrict__ me) {
  const int tid = threadIdx.x, w = tid >> 6, lane = tid & 63;
  const int s0 = blockIdx.x * 32;
  float mesum = 0.0f;
  for (int it = 0; it < 8; it++) {
    const int s = s0 + it * 4 + w;
    float logit = 0.0f;
#pragma unroll
    for (int p = 0; p < KS; p++)
      logit += part[((size_t)p * TS + s) * TE + lane];  // deterministic order
    // wave argmax, first-index tie-break (matches jnp.argmax)
    float mv = logit; int mi = lane;
#pragma unroll
    for (int off = 32; off; off >>= 1) {
      float ov = __shfl_xor(mv, off);
      int oi = __shfl_xor(mi, off);
      if (ov > mv || (ov == mv && oi < mi)) { mv = ov; mi = oi; }
    }
    float ex = expf(logit - mv);
    float sum = ex;
#pragma unroll
    for (int off = 32; off; off >>= 1) sum += __shfl_xor(sum, off);
    float g = ex / sum;
    mesum += g;
    if (lane == mi) { gate1[s] = g; idx1[s] = mi; }
  }
  __shared__ float red[4][64];
  red[w][lane] = mesum;
  __syncthreads();
  if (w == 0)
    atomicAdd(&me[lane], red[0][lane] + red[1][lane] + red[2][lane] + red[3][lane]);
}

// ==== K3: capacity rank (token order) + direct sparse scatter ====
// 64 blocks (1/expert) x 4 waves: pass A counts per wave-range, pass B
// ranks + scatters. Each token owned by exactly one expert -> no races.
__global__ __launch_bounds__(256) void k3_rank_scatter(
    const int* __restrict__ idx1, const float* __restrict__ gate1,
    int* __restrict__ counts, float* __restrict__ out) {
  const int e = blockIdx.x;
  const int w = threadIdx.x >> 6, lane = threadIdx.x & 63;
  const int s0 = w * (TS / 4);
  __shared__ int wcnt[4];

  int cnt = 0;
  for (int c = 0; c < TS / 4 / 64; c++) {           // 32 ballot steps
    int s = s0 + c * 64 + lane;
    cnt += __popcll(__ballot(idx1[s] == e));
  }
  if (lane == 0) wcnt[w] = cnt;
  __syncthreads();
  int base = 0;
  for (int j = 0; j < w; j++) base += wcnt[j];

  for (int c = 0; c < TS / 4 / 64; c++) {           // 32 more (L2-hot)
    int s = s0 + c * 64 + lane;
    bool m = (idx1[s] == e);
    unsigned long long mask = __ballot(m);
    if (m) {
      int p = base + __popcll(mask & ((1ull << lane) - 1ull));
      if (p < TCAP) {
        size_t off = 1 + ((size_t)s * TE + e) * (size_t)TCAP + (size_t)p;
        out[off] = gate1[s];          // combine_weights
        out[off + CWsz] = 1.0f;       // dispatch_mask
      }
    }
    base += __popcll(mask);
  }
  if (w == 3 && lane == 0) counts[e] = base;        // pre-drop exp_counts
}

// ============ K4: l_aux scalar + exp_counts (1 block, 64 thr) ============
__global__ void k4_laux(const float* __restrict__ me, const int* __restrict__ cnts,
                        float* __restrict__ out) {
  const int lane = threadIdx.x;
  float vv = (me[lane] / (float)TS) * ((float)cnts[lane] / (float)TS);
  float sum = vv;
#pragma unroll
  for (int off = 32; off; off >>= 1) sum += __shfl_xor(sum, off);
  if (lane == 0) out[0] = sum * (float)TE;
  out[1 + 2 * CWsz + lane] = (float)cnts[lane];
}

extern "C" void kernel_launch(void* const* d_in, const int* in_sizes, int n_in,
                              void* d_out, int out_size, void* d_ws, size_t ws_size,
                              hipStream_t stream) {
  const float* x  = (const float*)d_in[0];
  const float* wg = (const float*)d_in[1];
  float* out = (float*)d_out;

  float* part  = (float*)d_ws;                        // [KS][S][E] 16.8 MB
  float* gate1 = part + (size_t)KS * TS * TE;         // [S]
  int*   idx1  = (int*)(gate1 + TS);                  // [S]
  float* me    = (float*)(idx1 + TS);                 // [E]
  int*   cnts  = (int*)(me + TE);                     // [E]

  k1_fill_gemm<<<K1_GRID, 256, 0, stream>>>(x, wg, part, me, out);
  k2_softmax<<<TS / 32, 256, 0, stream>>>(part, gate1, idx1, me);
  k3_rank_scatter<<<TE, 256, 0, stream>>>(idx1, gate1, cnts, out);
  k4_laux<<<1, 64, 0, stream>>>(me, cnts, out);
}